// Round 5
// baseline (128.987 us; speedup 1.0000x reference)
//
#include <hip/hip_runtime.h>
#include <hip/hip_bf16.h>
#include <cstdint>
#include <cstddef>

typedef short bf16x8 __attribute__((ext_vector_type(8)));
typedef float f32x4 __attribute__((ext_vector_type(4)));

#define BN 8
#define TN 2048
#define CN 1024
#define HN 64

__device__ __forceinline__ unsigned short f2bf(float f) {
    unsigned int u = __float_as_uint(f);
    u += 0x7fffu + ((u >> 16) & 1u);
    return (unsigned short)(u >> 16);
}

// packed f32x2 -> bf16x2 (v_cvt_pk_bf16_f32), lo in low half
__device__ __forceinline__ int pk2(float lo, float hi) {
    float2 t; t.x = lo; t.y = hi;
    __hip_bfloat162 h = __float22bfloat162_rn(t);
    return *reinterpret_cast<int*>(&h);
}

// Build Wct[n][c] (bf16), n in [0,192): n<64 = Wq col h (pre-scaled by 0.125*log2e),
// 64..127 = Wk col, 128..191 = Wv col.  Source W is [C][H] row-major.
__global__ __launch_bounds__(256) void wconv_kernel(const float* __restrict__ Wq,
                                                    const float* __restrict__ Wk,
                                                    const float* __restrict__ Wv,
                                                    unsigned short* __restrict__ Wct) {
    int idx = blockIdx.x * 256 + threadIdx.x;   // 0..196607
    int n = idx >> 10;
    int c = idx & 1023;
    int m = n >> 6;
    int h = n & 63;
    const float* W = (m == 0) ? Wq : ((m == 1) ? Wk : Wv);
    float v = W[c * 64 + h];
    if (m == 0) v *= 0.18033688011112042f;  // (1/sqrt(64)) * log2(e)
    Wct[idx] = f2bf(v);
}

// Fused QKV projection v4: barrier-free, LDS-free, max-TLP.
// 512 blocks x 512 threads (8 waves) = 4096 waves = 4 waves/SIMD.
// Wave = (wr = M-half of 32-row block, wc = N-quarter): 16 rows x 48 cols.
// X streamed from global (32B/lane contiguous), W fragments from L2-resident Wct,
// fp32->bf16 via packed v_cvt_pk_bf16_f32.
__global__ __launch_bounds__(512) void proj_kernel(const float* __restrict__ X,
                                                   const unsigned short* __restrict__ Wct,
                                                   unsigned short* __restrict__ Qs,
                                                   unsigned short* __restrict__ Ks,
                                                   unsigned short* __restrict__ Vt) {
    const int tid = threadIdx.x;
    const int w   = tid >> 6;       // 0..7
    const int l   = tid & 63;
    const int lq  = l & 15;
    const int lg  = l >> 4;
    const int wr  = w >> 2;         // M-half
    const int wc  = w & 3;          // N-quarter
    const int rowbase = blockIdx.x * 32;

    const float* xb = X + (size_t)(rowbase + wr * 16 + lq) * CN;
    const unsigned short* wb0 = Wct + (size_t)(wc * 48 + 0 * 16 + lq) * CN;
    const unsigned short* wb1 = Wct + (size_t)(wc * 48 + 1 * 16 + lq) * CN;
    const unsigned short* wb2 = Wct + (size_t)(wc * 48 + 2 * 16 + lq) * CN;

    const f32x4 zero4 = {0.f, 0.f, 0.f, 0.f};
    f32x4 acc[3] = {zero4, zero4, zero4};

    #pragma unroll 2
    for (int kk = 0; kk < 32; ++kk) {
        const int k0 = kk * 32 + lg * 8;
        float4 x0 = *(const float4*)(xb + k0);
        float4 x1 = *(const float4*)(xb + k0 + 4);
        bf16x8 b0 = *(const bf16x8*)(wb0 + k0);
        bf16x8 b1 = *(const bf16x8*)(wb1 + k0);
        bf16x8 b2 = *(const bf16x8*)(wb2 + k0);
        union { bf16x8 v; int u[4]; } ua;
        ua.u[0] = pk2(x0.x, x0.y);
        ua.u[1] = pk2(x0.z, x0.w);
        ua.u[2] = pk2(x1.x, x1.y);
        ua.u[3] = pk2(x1.z, x1.w);
        acc[0] = __builtin_amdgcn_mfma_f32_16x16x32_bf16(ua.v, b0, acc[0], 0, 0, 0);
        acc[1] = __builtin_amdgcn_mfma_f32_16x16x32_bf16(ua.v, b1, acc[1], 0, 0, 0);
        acc[2] = __builtin_amdgcn_mfma_f32_16x16x32_bf16(ua.v, b2, acc[2], 0, 0, 0);
    }

    // D layout: col = lane&15 (W col), row = 4*(lane>>4) + reg (X row)
    #pragma unroll
    for (int j = 0; j < 3; ++j) {
        const int col = wc * 48 + j * 16 + lq;
        const int mtx = col >> 6;          // 0=Q, 1=K, 2=V
        const int h   = col & 63;
        #pragma unroll
        for (int i = 0; i < 4; ++i) {
            const int g = rowbase + wr * 16 + 4 * lg + i;
            const unsigned short val = f2bf(acc[j][i]);
            if (mtx == 0) {
                Qs[(size_t)g * 64 + h] = val;
            } else if (mtx == 1) {
                Ks[(size_t)g * 64 + h] = val;
            } else {
                const int bb = g >> 11, t = g & 2047;
                Vt[(size_t)((bb << 6) + h) * 2048 + t] = val;
            }
        }
    }
}

// Block-cooperative causal flash attention (unchanged from round 3).
// Block = (batch, q-tile pair {127-pr, pr}) -> exactly 65 key-tiles per block.
__global__ __launch_bounds__(256) void attn_kernel(const unsigned short* __restrict__ Qs,
                                                   const unsigned short* __restrict__ Ks,
                                                   const unsigned short* __restrict__ Vt,
                                                   float* __restrict__ Out) {
    __shared__ float lm[2][4][16];
    __shared__ float ll[2][4][16];
    __shared__ float facc[2][4][1024];

    const int tid = threadIdx.x;
    const int w  = tid >> 6;
    const int l  = tid & 63;
    const int lq = l & 15;
    const int lg = l >> 4;
    const int bid = blockIdx.x;
    const int b  = bid >> 6;
    const int pr = bid & 63;

    const unsigned short* Qb = Qs + (size_t)b * TN * 64;
    const unsigned short* Kb = Ks + (size_t)b * TN * 64;
    const unsigned short* Vb = Vt + (size_t)b * 64 * TN;

    int koff[4];
    #pragma unroll
    for (int fa = 0; fa < 2; ++fa)
        #pragma unroll
        for (int ks = 0; ks < 2; ++ks)
            koff[fa * 2 + ks] = (fa * 16 + lq) * 64 + ks * 32 + lg * 8;
    int voff[4];
    #pragma unroll
    for (int nf = 0; nf < 4; ++nf)
        voff[nf] = (nf * 16 + lq) * 2048 + 4 * lg;

    const f32x4 zero4 = {0.f, 0.f, 0.f, 0.f};

    #pragma unroll
    for (int X = 0; X < 2; ++X) {
        const int qt = (X == 0) ? (127 - pr) : pr;
        const int q0 = qt * 16;
        const int nt = (qt >> 1) + 1;

        bf16x8 qa0 = *(const bf16x8*)(Qb + (size_t)(q0 + lq) * 64 + 0 * 32 + lg * 8);
        bf16x8 qa1 = *(const bf16x8*)(Qb + (size_t)(q0 + lq) * 64 + 1 * 32 + lg * 8);

        f32x4 acc[4] = {zero4, zero4, zero4, zero4};
        float mrow = -1e30f;
        float lrow = 0.f;

        bf16x8 Kc[4], Vc[4], Kn[4], Vn[4];
        int kt = w;
        if (kt < nt) {
            const size_t kb = (size_t)kt * 2048;
            #pragma unroll
            for (int i = 0; i < 4; ++i)
                Kc[i] = *(const bf16x8*)(Kb + kb + koff[i]);
            #pragma unroll
            for (int nf = 0; nf < 4; ++nf) {
                union { bf16x8 v; ushort4 h[2]; } u;
                u.h[0] = *(const ushort4*)(Vb + voff[nf] + kt * 32);
                u.h[1] = *(const ushort4*)(Vb + voff[nf] + kt * 32 + 16);
                Vc[nf] = u.v;
            }
        }

        for (; kt < nt; kt += 4) {
            const int ktn = kt + 4;
            if (ktn < nt) {
                const size_t kb = (size_t)ktn * 2048;
                #pragma unroll
                for (int i = 0; i < 4; ++i)
                    Kn[i] = *(const bf16x8*)(Kb + kb + koff[i]);
                #pragma unroll
                for (int nf = 0; nf < 4; ++nf) {
                    union { bf16x8 v; ushort4 h[2]; } u;
                    u.h[0] = *(const ushort4*)(Vb + voff[nf] + ktn * 32);
                    u.h[1] = *(const ushort4*)(Vb + voff[nf] + ktn * 32 + 16);
                    Vn[nf] = u.v;
                }
            }

            const int key0 = kt * 32;
            f32x4 s[2];
            s[0] = __builtin_amdgcn_mfma_f32_16x16x32_bf16(Kc[0], qa0, zero4, 0, 0, 0);
            s[0] = __builtin_amdgcn_mfma_f32_16x16x32_bf16(Kc[1], qa1, s[0], 0, 0, 0);
            s[1] = __builtin_amdgcn_mfma_f32_16x16x32_bf16(Kc[2], qa0, zero4, 0, 0, 0);
            s[1] = __builtin_amdgcn_mfma_f32_16x16x32_bf16(Kc[3], qa1, s[1], 0, 0, 0);

            if (kt == nt - 1) {
                const int q = q0 + lq;
                #pragma unroll
                for (int fa = 0; fa < 2; ++fa)
                    #pragma unroll
                    for (int r = 0; r < 4; ++r) {
                        const int key = key0 + fa * 16 + 4 * lg + r;
                        if (key > q) s[fa][r] = -1e30f;
                    }
            }

            float m1 = fmaxf(fmaxf(s[0][0], s[0][1]), s[0][2]);
            float m2 = fmaxf(fmaxf(s[0][3], s[1][0]), s[1][1]);
            float m3 = fmaxf(fmaxf(s[1][2], s[1][3]), m1);
            float tm = fmaxf(m2, m3);
            tm = fmaxf(tm, __shfl_xor(tm, 16));
            tm = fmaxf(tm, __shfl_xor(tm, 32));

            if (!__all(tm <= mrow + 8.0f)) {
                const float mnew = fmaxf(mrow, tm);
                const float cc = __builtin_amdgcn_exp2f(mrow - mnew);
                lrow *= cc;
                float cb[4];
                #pragma unroll
                for (int i = 0; i < 4; ++i) cb[i] = __shfl(cc, 4 * lg + i);
                #pragma unroll
                for (int nf = 0; nf < 4; ++nf)
                    #pragma unroll
                    for (int i = 0; i < 4; ++i) acc[nf][i] *= cb[i];
                mrow = mnew;
            }

            float p[2][4];
            float psum = 0.f;
            #pragma unroll
            for (int fa = 0; fa < 2; ++fa)
                #pragma unroll
                for (int r = 0; r < 4; ++r) {
                    p[fa][r] = __builtin_amdgcn_exp2f(s[fa][r] - mrow);
                    psum += p[fa][r];
                }
            psum += __shfl_xor(psum, 16);
            psum += __shfl_xor(psum, 32);
            lrow += psum;

            bf16x8 pa;
            pa[0] = (short)f2bf(p[0][0]); pa[1] = (short)f2bf(p[0][1]);
            pa[2] = (short)f2bf(p[0][2]); pa[3] = (short)f2bf(p[0][3]);
            pa[4] = (short)f2bf(p[1][0]); pa[5] = (short)f2bf(p[1][1]);
            pa[6] = (short)f2bf(p[1][2]); pa[7] = (short)f2bf(p[1][3]);

            acc[0] = __builtin_amdgcn_mfma_f32_16x16x32_bf16(pa, Vc[0], acc[0], 0, 0, 0);
            acc[1] = __builtin_amdgcn_mfma_f32_16x16x32_bf16(pa, Vc[1], acc[1], 0, 0, 0);
            acc[2] = __builtin_amdgcn_mfma_f32_16x16x32_bf16(pa, Vc[2], acc[2], 0, 0, 0);
            acc[3] = __builtin_amdgcn_mfma_f32_16x16x32_bf16(pa, Vc[3], acc[3], 0, 0, 0);

            #pragma unroll
            for (int i = 0; i < 4; ++i) { Kc[i] = Kn[i]; Vc[i] = Vn[i]; }
        }

        if (lg == 0) {
            lm[X][w][lq] = mrow;
            ll[X][w][lq] = lrow;
        }
        #pragma unroll
        for (int nf = 0; nf < 4; ++nf)
            #pragma unroll
            for (int i = 0; i < 4; ++i)
                facc[X][w][(4 * lg + i) * 64 + nf * 16 + lq] = acc[nf][i];
    }

    __syncthreads();

    #pragma unroll
    for (int X = 0; X < 2; ++X) {
        const int qt = (X == 0) ? (127 - pr) : pr;
        const int q0 = qt * 16;
        #pragma unroll
        for (int ii = 0; ii < 4; ++ii) {
            const int e = tid + ii * 256;
            const int q = e >> 6;
            const int h = e & 63;
            const float M = fmaxf(fmaxf(lm[X][0][q], lm[X][1][q]),
                                  fmaxf(lm[X][2][q], lm[X][3][q]));
            float L = 0.f, O = 0.f;
            #pragma unroll
            for (int c = 0; c < 4; ++c) {
                const float wgt = __builtin_amdgcn_exp2f(lm[X][c][q] - M);
                L += wgt * ll[X][c][q];
                O += wgt * facc[X][c][q * 64 + h];
            }
            Out[((size_t)b * TN + q0 + q) * 64 + h] = O / L;
        }
    }
}

extern "C" void kernel_launch(void* const* d_in, const int* in_sizes, int n_in,
                              void* d_out, int out_size, void* d_ws, size_t ws_size,
                              hipStream_t stream) {
    const float* X  = (const float*)d_in[0];
    const float* Wq = (const float*)d_in[1];
    const float* Wk = (const float*)d_in[2];
    const float* Wv = (const float*)d_in[3];
    float* Out = (float*)d_out;

    char* ws = (char*)d_ws;
    unsigned short* Wct = (unsigned short*)(ws);                 // 384 KB (pad 512 KB)
    unsigned short* Qs  = (unsigned short*)(ws + (512u << 10));  // 2 MB
    unsigned short* Ks  = Qs + (size_t)16384 * 64;               // 2 MB
    unsigned short* Vt  = Ks + (size_t)16384 * 64;               // 2 MB

    hipLaunchKernelGGL(wconv_kernel, dim3(768), dim3(256), 0, stream, Wq, Wk, Wv, Wct);
    hipLaunchKernelGGL(proj_kernel,  dim3(512), dim3(512), 0, stream, X, Wct, Qs, Ks, Vt);
    hipLaunchKernelGGL(attn_kernel,  dim3(512), dim3(256), 0, stream, Qs, Ks, Vt, Out);
}

// Round 6
// 68.388 us; speedup vs baseline: 1.8861x; 1.8861x over previous
//
#include <hip/hip_runtime.h>
#include <hip/hip_bf16.h>
#include <cstdint>
#include <cstddef>

typedef short bf16x8 __attribute__((ext_vector_type(8)));
typedef float f32x4 __attribute__((ext_vector_type(4)));

#define BN 8
#define TN 2048
#define CN 1024
#define HN 64

__device__ __forceinline__ unsigned short f2bf(float f) {
    unsigned int u = __float_as_uint(f);
    u += 0x7fffu + ((u >> 16) & 1u);
    return (unsigned short)(u >> 16);
}

// packed f32x2 -> bf16x2 (v_cvt_pk_bf16_f32), lo in low half
__device__ __forceinline__ int pk2(float lo, float hi) {
    float2 t; t.x = lo; t.y = hi;
    __hip_bfloat162 h = __float22bfloat162_rn(t);
    return *reinterpret_cast<int*>(&h);
}

// Build Wp: W in MFMA-B-fragment-packed order.
// Logical Wct[n][c], n in [0,192): n<64 = Wq col h (pre-scaled by 0.125*log2e),
// 64..127 = Wk, 128..191 = Wv.  Fragment (tile=n>>4, kk=c>>5): lane = lg*16+lq
// (lg=(c>>3)&3, lq=n&15), elem e=c&7.
// idx = ((tile*32+kk)*64 + lg*16 + lq)*8 + e  -> wave loads are lane-contiguous.
__global__ __launch_bounds__(256) void wconv_kernel(const float* __restrict__ Wq,
                                                    const float* __restrict__ Wk,
                                                    const float* __restrict__ Wv,
                                                    unsigned short* __restrict__ Wp) {
    int idx = blockIdx.x * 256 + threadIdx.x;   // 0..196607
    int n = idx >> 10;
    int c = idx & 1023;
    int m = n >> 6;
    int h = n & 63;
    const float* W = (m == 0) ? Wq : ((m == 1) ? Wk : Wv);
    float v = W[c * 64 + h];
    if (m == 0) v *= 0.18033688011112042f;  // (1/sqrt(64)) * log2(e)
    const int tile = n >> 4, lq = n & 15;
    const int kk = c >> 5, lg = (c >> 3) & 3, e = c & 7;
    Wp[(size_t)(((tile * 32 + kk) * 64 + lg * 16 + lq) * 8 + e)] = f2bf(v);
}

// Fused QKV projection v5: barrier-free, LDS-free, fragment-packed W,
// fully-unrolled K-loop with explicit 2-stage register pipeline.
// 512 blocks x 512 threads (8 waves).  Wave = (wr M-half, wc N-quarter):
// 16 rows x 48 cols.  Outputs: Qs row-major, Kp/Vp fragment-packed for attn.
__global__ __launch_bounds__(512) void proj_kernel(const float* __restrict__ X,
                                                   const unsigned short* __restrict__ Wp,
                                                   unsigned short* __restrict__ Qs,
                                                   unsigned short* __restrict__ Kp,
                                                   unsigned short* __restrict__ Vp) {
    const int tid = threadIdx.x;
    const int w   = tid >> 6;       // 0..7
    const int l   = tid & 63;
    const int lq  = l & 15;
    const int lg  = l >> 4;
    const int wr  = w >> 2;         // M-half
    const int wc  = w & 3;          // N-quarter
    const int rowbase = blockIdx.x * 32;

    const float* xb = X + (size_t)(rowbase + wr * 16 + lq) * CN;
    // fragment-packed W: tile stride 16384 elems, kk stride 512 elems
    const unsigned short* wp = Wp + (size_t)(wc * 3) * 16384 + (size_t)l * 8;

    const f32x4 zero4 = {0.f, 0.f, 0.f, 0.f};
    f32x4 acc[3] = {zero4, zero4, zero4};

    // 2-stage software pipeline with named stage registers; full unroll
    float4 xA0, xA1, xB0, xB1;
    bf16x8 bA0, bA1, bA2, bB0, bB1, bB2;

    {
        const int k0 = lg * 8;
        xA0 = *(const float4*)(xb + k0);
        xA1 = *(const float4*)(xb + k0 + 4);
        bA0 = *(const bf16x8*)(wp);
        bA1 = *(const bf16x8*)(wp + 16384);
        bA2 = *(const bf16x8*)(wp + 32768);
    }

    #pragma unroll
    for (int kk = 0; kk < 32; ++kk) {
        const bool even = (kk & 1) == 0;
        if (kk + 1 < 32) {   // issue next-stage loads before current compute
            const int k0 = (kk + 1) * 32 + lg * 8;
            const int wo = (kk + 1) * 512;
            if (even) {
                xB0 = *(const float4*)(xb + k0);
                xB1 = *(const float4*)(xb + k0 + 4);
                bB0 = *(const bf16x8*)(wp + wo);
                bB1 = *(const bf16x8*)(wp + 16384 + wo);
                bB2 = *(const bf16x8*)(wp + 32768 + wo);
            } else {
                xA0 = *(const float4*)(xb + k0);
                xA1 = *(const float4*)(xb + k0 + 4);
                bA0 = *(const bf16x8*)(wp + wo);
                bA1 = *(const bf16x8*)(wp + 16384 + wo);
                bA2 = *(const bf16x8*)(wp + 32768 + wo);
            }
        }
        const float4 x0 = even ? xA0 : xB0;
        const float4 x1 = even ? xA1 : xB1;
        const bf16x8 b0 = even ? bA0 : bB0;
        const bf16x8 b1 = even ? bA1 : bB1;
        const bf16x8 b2 = even ? bA2 : bB2;
        union { bf16x8 v; int u[4]; } ua;
        ua.u[0] = pk2(x0.x, x0.y);
        ua.u[1] = pk2(x0.z, x0.w);
        ua.u[2] = pk2(x1.x, x1.y);
        ua.u[3] = pk2(x1.z, x1.w);
        acc[0] = __builtin_amdgcn_mfma_f32_16x16x32_bf16(ua.v, b0, acc[0], 0, 0, 0);
        acc[1] = __builtin_amdgcn_mfma_f32_16x16x32_bf16(ua.v, b1, acc[1], 0, 0, 0);
        acc[2] = __builtin_amdgcn_mfma_f32_16x16x32_bf16(ua.v, b2, acc[2], 0, 0, 0);
    }

    // D layout: col = lane&15 (W col), row = 4*(lane>>4) + reg (X row)
    #pragma unroll
    for (int j = 0; j < 3; ++j) {
        const int col = wc * 48 + j * 16 + lq;
        const int mtx = col >> 6;          // 0=Q, 1=K, 2=V
        const int h   = col & 63;
        #pragma unroll
        for (int i = 0; i < 4; ++i) {
            const int g = rowbase + wr * 16 + 4 * lg + i;   // global token row
            const unsigned short val = f2bf(acc[j][i]);
            const int b = g >> 11, tloc = g & 2047;
            const int kt = tloc >> 5;
            if (mtx == 0) {
                Qs[(size_t)g * 64 + h] = val;
            } else if (mtx == 1) {
                // K fragment-packed: frag = fa*2+ks, lane = lgk*16+lqk, elem e
                const int fa = (tloc >> 4) & 1, lqk = tloc & 15;
                const int ks = h >> 5, lgk = (h >> 3) & 3, e = h & 7;
                Kp[(size_t)(b * 64 + kt) * 2048 + (fa * 2 + ks) * 512 +
                   (lgk * 16 + lqk) * 8 + e] = val;
            } else {
                // V fragment-packed: frag = nf, lane = lgv*16+lqv, elem e
                const int tt = tloc & 31;
                const int lgv = (tt & 15) >> 2;
                const int e = (tt < 16) ? (tt & 3) : 4 + (tt & 3);
                const int nf = h >> 4, lqv = h & 15;
                Vp[(size_t)(b * 64 + kt) * 2048 + nf * 512 +
                   (lgv * 16 + lqv) * 8 + e] = val;
            }
        }
    }
}

// Block-cooperative causal flash attention, fragment-packed K/V.
// Block = (qt, b): 1024 blocks x 4 waves; heavy q-tiles launch first.
// Waves split the q-tile's key-tiles round-robin; partials merged in LDS.
// S^T = mfma(K, Q): lane&15 = query, key = 16*fa + 4*(lane>>4) + reg.
__global__ __launch_bounds__(256) void attn_kernel(const unsigned short* __restrict__ Qs,
                                                   const unsigned short* __restrict__ Kp,
                                                   const unsigned short* __restrict__ Vp,
                                                   float* __restrict__ Out) {
    __shared__ float lm[4][16];
    __shared__ float ll[4][16];
    __shared__ float facc[4][1024];

    const int tid = threadIdx.x;
    const int w  = tid >> 6;
    const int l  = tid & 63;
    const int lq = l & 15;
    const int lg = l >> 4;
    const int bid = blockIdx.x;
    const int qt = 127 - (bid >> 3);   // heavy first
    const int b  = bid & 7;
    const int q0 = qt * 16;
    const int nt = (qt >> 1) + 1;

    const unsigned short* Qb = Qs + (size_t)b * TN * 64;
    const unsigned short* KVbase_k = Kp + (size_t)b * 64 * 2048 + (size_t)l * 8;
    const unsigned short* KVbase_v = Vp + (size_t)b * 64 * 2048 + (size_t)l * 8;

    const f32x4 zero4 = {0.f, 0.f, 0.f, 0.f};

    bf16x8 qa0 = *(const bf16x8*)(Qb + (size_t)(q0 + lq) * 64 + lg * 8);
    bf16x8 qa1 = *(const bf16x8*)(Qb + (size_t)(q0 + lq) * 64 + 32 + lg * 8);

    f32x4 acc[4] = {zero4, zero4, zero4, zero4};
    float mrow = -1e30f;
    float lrow = 0.f;

    bf16x8 Kc[4], Vc[4], Kn[4], Vn[4];
    int kt = w;
    if (kt < nt) {
        const size_t tb = (size_t)kt * 2048;
        #pragma unroll
        for (int i = 0; i < 4; ++i) {
            Kc[i] = *(const bf16x8*)(KVbase_k + tb + i * 512);
            Vc[i] = *(const bf16x8*)(KVbase_v + tb + i * 512);
        }
    }

    for (; kt < nt; kt += 4) {
        const int ktn = kt + 4;
        if (ktn < nt) {   // prefetch next tile (coalesced 1KB loads)
            const size_t tb = (size_t)ktn * 2048;
            #pragma unroll
            for (int i = 0; i < 4; ++i) {
                Kn[i] = *(const bf16x8*)(KVbase_k + tb + i * 512);
                Vn[i] = *(const bf16x8*)(KVbase_v + tb + i * 512);
            }
        }

        const int key0 = kt * 32;
        f32x4 s[2];
        s[0] = __builtin_amdgcn_mfma_f32_16x16x32_bf16(Kc[0], qa0, zero4, 0, 0, 0);
        s[0] = __builtin_amdgcn_mfma_f32_16x16x32_bf16(Kc[1], qa1, s[0], 0, 0, 0);
        s[1] = __builtin_amdgcn_mfma_f32_16x16x32_bf16(Kc[2], qa0, zero4, 0, 0, 0);
        s[1] = __builtin_amdgcn_mfma_f32_16x16x32_bf16(Kc[3], qa1, s[1], 0, 0, 0);

        if (kt == nt - 1) {   // only the diagonal tile needs masking
            const int q = q0 + lq;
            #pragma unroll
            for (int fa = 0; fa < 2; ++fa)
                #pragma unroll
                for (int r = 0; r < 4; ++r) {
                    const int key = key0 + fa * 16 + 4 * lg + r;
                    if (key > q) s[fa][r] = -1e30f;
                }
        }

        float m1 = fmaxf(fmaxf(s[0][0], s[0][1]), s[0][2]);
        float m2 = fmaxf(fmaxf(s[0][3], s[1][0]), s[1][1]);
        float m3 = fmaxf(fmaxf(s[1][2], s[1][3]), m1);
        float tm = fmaxf(m2, m3);
        tm = fmaxf(tm, __shfl_xor(tm, 16));
        tm = fmaxf(tm, __shfl_xor(tm, 32));

        // defer-max: only rescale when max grows by > 8 (P bounded by 2^8)
        if (!__all(tm <= mrow + 8.0f)) {
            const float mnew = fmaxf(mrow, tm);
            const float cc = __builtin_amdgcn_exp2f(mrow - mnew);
            lrow *= cc;
            float cb[4];
            #pragma unroll
            for (int i = 0; i < 4; ++i) cb[i] = __shfl(cc, 4 * lg + i);
            #pragma unroll
            for (int nf = 0; nf < 4; ++nf)
                #pragma unroll
                for (int i = 0; i < 4; ++i) acc[nf][i] *= cb[i];
            mrow = mnew;
        }

        float p[2][4];
        float psum = 0.f;
        #pragma unroll
        for (int fa = 0; fa < 2; ++fa)
            #pragma unroll
            for (int r = 0; r < 4; ++r) {
                p[fa][r] = __builtin_amdgcn_exp2f(s[fa][r] - mrow);
                psum += p[fa][r];
            }
        psum += __shfl_xor(psum, 16);
        psum += __shfl_xor(psum, 32);
        lrow += psum;

        bf16x8 pa;
        pa[0] = (short)f2bf(p[0][0]); pa[1] = (short)f2bf(p[0][1]);
        pa[2] = (short)f2bf(p[0][2]); pa[3] = (short)f2bf(p[0][3]);
        pa[4] = (short)f2bf(p[1][0]); pa[5] = (short)f2bf(p[1][1]);
        pa[6] = (short)f2bf(p[1][2]); pa[7] = (short)f2bf(p[1][3]);

        acc[0] = __builtin_amdgcn_mfma_f32_16x16x32_bf16(pa, Vc[0], acc[0], 0, 0, 0);
        acc[1] = __builtin_amdgcn_mfma_f32_16x16x32_bf16(pa, Vc[1], acc[1], 0, 0, 0);
        acc[2] = __builtin_amdgcn_mfma_f32_16x16x32_bf16(pa, Vc[2], acc[2], 0, 0, 0);
        acc[3] = __builtin_amdgcn_mfma_f32_16x16x32_bf16(pa, Vc[3], acc[3], 0, 0, 0);

        #pragma unroll
        for (int i = 0; i < 4; ++i) { Kc[i] = Kn[i]; Vc[i] = Vn[i]; }
    }

    // store partial state to LDS
    if (lg == 0) {
        lm[w][lq] = mrow;
        ll[w][lq] = lrow;
    }
    #pragma unroll
    for (int nf = 0; nf < 4; ++nf)
        #pragma unroll
        for (int i = 0; i < 4; ++i)
            facc[w][(4 * lg + i) * 64 + nf * 16 + lq] = acc[nf][i];

    __syncthreads();

    // merge 4 wave-partials and write Out
    #pragma unroll
    for (int ii = 0; ii < 4; ++ii) {
        const int e = tid + ii * 256;
        const int q = e >> 6;
        const int h = e & 63;
        const float M = fmaxf(fmaxf(lm[0][q], lm[1][q]),
                              fmaxf(lm[2][q], lm[3][q]));
        float L = 0.f, O = 0.f;
        #pragma unroll
        for (int c = 0; c < 4; ++c) {
            const float wgt = __builtin_amdgcn_exp2f(lm[c][q] - M);
            L += wgt * ll[c][q];
            O += wgt * facc[c][q * 64 + h];
        }
        Out[((size_t)b * TN + q0 + q) * 64 + h] = O / L;
    }
}

extern "C" void kernel_launch(void* const* d_in, const int* in_sizes, int n_in,
                              void* d_out, int out_size, void* d_ws, size_t ws_size,
                              hipStream_t stream) {
    const float* X  = (const float*)d_in[0];
    const float* Wq = (const float*)d_in[1];
    const float* Wk = (const float*)d_in[2];
    const float* Wv = (const float*)d_in[3];
    float* Out = (float*)d_out;

    char* ws = (char*)d_ws;
    unsigned short* Wp = (unsigned short*)(ws);                 // 384 KB (pad 512 KB)
    unsigned short* Qs = (unsigned short*)(ws + (512u << 10));  // 2 MB
    unsigned short* Kp = Qs + (size_t)16384 * 64;               // 2 MB
    unsigned short* Vp = Kp + (size_t)16384 * 64;               // 2 MB

    hipLaunchKernelGGL(wconv_kernel, dim3(768), dim3(256), 0, stream, Wq, Wk, Wv, Wp);
    hipLaunchKernelGGL(proj_kernel,  dim3(512), dim3(512), 0, stream, X, Wp, Qs, Kp, Vp);
    hipLaunchKernelGGL(attn_kernel,  dim3(1024), dim3(256), 0, stream, Qs, Kp, Vp, Out);
}

// Round 7
// 42.966 us; speedup vs baseline: 3.0021x; 1.5917x over previous
//
#include <hip/hip_runtime.h>
#include <hip/hip_bf16.h>
#include <cstdint>
#include <cstddef>

typedef short bf16x8 __attribute__((ext_vector_type(8)));
typedef float f32x4 __attribute__((ext_vector_type(4)));

#define BN 8
#define TN 2048
#define CN 1024
#define HN 64

__device__ __forceinline__ unsigned short f2bf(float f) {
    unsigned int u = __float_as_uint(f);
    u += 0x7fffu + ((u >> 16) & 1u);
    return (unsigned short)(u >> 16);
}

// packed f32x2 -> bf16x2 (v_cvt_pk_bf16_f32), lo in low half
__device__ __forceinline__ int pk2(float lo, float hi) {
    float2 t; t.x = lo; t.y = hi;
    __hip_bfloat162 h = __float22bfloat162_rn(t);
    return *reinterpret_cast<int*>(&h);
}

// Build Wp: W in MFMA-B-fragment-packed order.
// Logical Wct[n][c], n in [0,192): n<64 = Wq col h (pre-scaled by 0.125*log2e),
// 64..127 = Wk, 128..191 = Wv.  Fragment (tile=n>>4, kk=c>>5): lane = lg*16+lq
// (lg=(c>>3)&3, lq=n&15), elem e=c&7.
// idx = ((tile*32+kk)*64 + lg*16 + lq)*8 + e  -> wave loads are lane-contiguous.
__global__ __launch_bounds__(256) void wconv_kernel(const float* __restrict__ Wq,
                                                    const float* __restrict__ Wk,
                                                    const float* __restrict__ Wv,
                                                    unsigned short* __restrict__ Wp) {
    int idx = blockIdx.x * 256 + threadIdx.x;   // 0..196607
    int n = idx >> 10;
    int c = idx & 1023;
    int m = n >> 6;
    int h = n & 63;
    const float* W = (m == 0) ? Wq : ((m == 1) ? Wk : Wv);
    float v = W[c * 64 + h];
    if (m == 0) v *= 0.18033688011112042f;  // (1/sqrt(64)) * log2(e)
    const int tile = n >> 4, lq = n & 15;
    const int kk = c >> 5, lg = (c >> 3) & 3, e = c & 7;
    Wp[(size_t)(((tile * 32 + kk) * 64 + lg * 16 + lq) * 8 + e)] = f2bf(v);
}

// Fused QKV projection v7: m97-style double-buffered LDS pipeline, reg-staged.
// 512 blocks x 512 threads (8 waves).  BM=32 rows, BN=192 (all cols), BK=64.
// LDS: X as bf16 [2][32][64] (converted once at staging, XOR-swizzled rows),
//      W fragment-packed linear [2][12288] (conflict-free by construction).
// Per K-step: issue next-step global loads -> compute cur from LDS ->
// cvt+ds_write next -> one __syncthreads().
__global__ __launch_bounds__(512) void proj_kernel(const float* __restrict__ X,
                                                   const unsigned short* __restrict__ Wp,
                                                   unsigned short* __restrict__ Qs,
                                                   unsigned short* __restrict__ Kp,
                                                   unsigned short* __restrict__ Vp) {
    __shared__ short Xs[2][32 * 64];      // 2 x 4 KB bf16
    __shared__ short Wsh[2][12288];       // 2 x 24 KB bf16

    const int tid = threadIdx.x;
    const int w   = tid >> 6;       // 0..7
    const int l   = tid & 63;
    const int lq  = l & 15;
    const int lg  = l >> 4;
    const int wr  = w >> 2;         // M-half
    const int wc  = w & 3;          // N-quarter
    const int rowbase = blockIdx.x * 32;

    // --- staging addresses (per thread) ---
    const int xrow = tid >> 4;             // 0..31
    const int xcol = (tid & 15) * 4;       // 0..60 (floats)
    const float* xsrc = X + (size_t)(rowbase + xrow) * CN + xcol;
    const int xdst = xrow * 128 + (((tid & 15) * 8) ^ ((xrow & 7) << 4));  // byte

    int wsrcoff[3], wdst[3];
    #pragma unroll
    for (int j = 0; j < 3; ++j) {
        const int el  = j * 4096 + tid * 8;       // 0..12287
        const int blk = el >> 9;                  // (tile,kkL) block of 512 elems
        const int t   = blk >> 1, kkL = blk & 1;
        wsrcoff[j] = (t * 32 + kkL) * 512 + (el & 511);
        wdst[j]    = el * 2;                      // byte, linear
    }

    // --- compute-side LDS addresses (per lane) ---
    const int arow = wr * 16 + lq;
    int aaddr[2];
    #pragma unroll
    for (int kkL = 0; kkL < 2; ++kkL)
        aaddr[kkL] = arow * 128 + (((kkL * 64 + lg * 16)) ^ ((arow & 7) << 4));
    int baddr[2][3];
    #pragma unroll
    for (int kkL = 0; kkL < 2; ++kkL)
        #pragma unroll
        for (int jj = 0; jj < 3; ++jj)
            baddr[kkL][jj] = (((wc * 3 + jj) * 2 + kkL) * 64 + l) * 16;  // byte

    const f32x4 zero4 = {0.f, 0.f, 0.f, 0.f};
    f32x4 acc[3] = {zero4, zero4, zero4};

    // --- prologue: stage step 0 into buffer 0 ---
    {
        float4 xr = *(const float4*)(xsrc);
        bf16x8 wreg0 = *(const bf16x8*)(Wp + wsrcoff[0]);
        bf16x8 wreg1 = *(const bf16x8*)(Wp + wsrcoff[1]);
        bf16x8 wreg2 = *(const bf16x8*)(Wp + wsrcoff[2]);
        int2 xc; xc.x = pk2(xr.x, xr.y); xc.y = pk2(xr.z, xr.w);
        *(int2*)((char*)Xs[0] + xdst) = xc;
        *(bf16x8*)((char*)Wsh[0] + wdst[0]) = wreg0;
        *(bf16x8*)((char*)Wsh[0] + wdst[1]) = wreg1;
        *(bf16x8*)((char*)Wsh[0] + wdst[2]) = wreg2;
        __syncthreads();
    }

    for (int s = 0; s < 16; ++s) {
        const int cur = s & 1;
        // 1) issue next step's global loads (latency hides under compute)
        float4 xr;
        bf16x8 wreg0, wreg1, wreg2;
        const bool more = (s + 1) < 16;
        if (more) {
            xr    = *(const float4*)(xsrc + (s + 1) * 64);
            wreg0 = *(const bf16x8*)(Wp + (s + 1) * 1024 + wsrcoff[0]);
            wreg1 = *(const bf16x8*)(Wp + (s + 1) * 1024 + wsrcoff[1]);
            wreg2 = *(const bf16x8*)(Wp + (s + 1) * 1024 + wsrcoff[2]);
        }
        // 2) compute current buffer
        #pragma unroll
        for (int kkL = 0; kkL < 2; ++kkL) {
            bf16x8 a  = *(const bf16x8*)((char*)Xs[cur] + aaddr[kkL]);
            bf16x8 b0 = *(const bf16x8*)((char*)Wsh[cur] + baddr[kkL][0]);
            bf16x8 b1 = *(const bf16x8*)((char*)Wsh[cur] + baddr[kkL][1]);
            bf16x8 b2 = *(const bf16x8*)((char*)Wsh[cur] + baddr[kkL][2]);
            acc[0] = __builtin_amdgcn_mfma_f32_16x16x32_bf16(a, b0, acc[0], 0, 0, 0);
            acc[1] = __builtin_amdgcn_mfma_f32_16x16x32_bf16(a, b1, acc[1], 0, 0, 0);
            acc[2] = __builtin_amdgcn_mfma_f32_16x16x32_bf16(a, b2, acc[2], 0, 0, 0);
        }
        // 3) convert + write next buffer
        if (more) {
            const int nxt = cur ^ 1;
            int2 xc; xc.x = pk2(xr.x, xr.y); xc.y = pk2(xr.z, xr.w);
            *(int2*)((char*)Xs[nxt] + xdst) = xc;
            *(bf16x8*)((char*)Wsh[nxt] + wdst[0]) = wreg0;
            *(bf16x8*)((char*)Wsh[nxt] + wdst[1]) = wreg1;
            *(bf16x8*)((char*)Wsh[nxt] + wdst[2]) = wreg2;
        }
        // 4) one barrier per K-step
        __syncthreads();
    }

    // D layout: col = lane&15 (W col), row = 4*(lane>>4) + reg (X row)
    #pragma unroll
    for (int j = 0; j < 3; ++j) {
        const int col = wc * 48 + j * 16 + lq;
        const int mtx = col >> 6;          // 0=Q, 1=K, 2=V
        const int h   = col & 63;
        #pragma unroll
        for (int i = 0; i < 4; ++i) {
            const int g = rowbase + wr * 16 + 4 * lg + i;   // global token row
            const unsigned short val = f2bf(acc[j][i]);
            const int b = g >> 11, tloc = g & 2047;
            const int kt = tloc >> 5;
            if (mtx == 0) {
                Qs[(size_t)g * 64 + h] = val;
            } else if (mtx == 1) {
                // K fragment-packed: frag = fa*2+ks, lane = lgk*16+lqk, elem e
                const int fa = (tloc >> 4) & 1, lqk = tloc & 15;
                const int ks = h >> 5, lgk = (h >> 3) & 3, e = h & 7;
                Kp[(size_t)(b * 64 + kt) * 2048 + (fa * 2 + ks) * 512 +
                   (lgk * 16 + lqk) * 8 + e] = val;
            } else {
                // V fragment-packed: frag = nf, lane = lgv*16+lqv, elem e
                const int tt = tloc & 31;
                const int lgv = (tt & 15) >> 2;
                const int e = (tt < 16) ? (tt & 3) : 4 + (tt & 3);
                const int nf = h >> 4, lqv = h & 15;
                Vp[(size_t)(b * 64 + kt) * 2048 + nf * 512 +
                   (lgv * 16 + lqv) * 8 + e] = val;
            }
        }
    }
}

// Block-cooperative causal flash attention, fragment-packed K/V.
// Block = (qt, b): 1024 blocks x 4 waves; heavy q-tiles launch first.
// Waves split the q-tile's key-tiles round-robin; partials merged in LDS.
// S^T = mfma(K, Q): lane&15 = query, key = 16*fa + 4*(lane>>4) + reg.
__global__ __launch_bounds__(256) void attn_kernel(const unsigned short* __restrict__ Qs,
                                                   const unsigned short* __restrict__ Kp,
                                                   const unsigned short* __restrict__ Vp,
                                                   float* __restrict__ Out) {
    __shared__ float lm[4][16];
    __shared__ float ll[4][16];
    __shared__ float facc[4][1024];

    const int tid = threadIdx.x;
    const int w  = tid >> 6;
    const int l  = tid & 63;
    const int lq = l & 15;
    const int lg = l >> 4;
    const int bid = blockIdx.x;
    const int qt = 127 - (bid >> 3);   // heavy first
    const int b  = bid & 7;
    const int q0 = qt * 16;
    const int nt = (qt >> 1) + 1;

    const unsigned short* Qb = Qs + (size_t)b * TN * 64;
    const unsigned short* KVbase_k = Kp + (size_t)b * 64 * 2048 + (size_t)l * 8;
    const unsigned short* KVbase_v = Vp + (size_t)b * 64 * 2048 + (size_t)l * 8;

    const f32x4 zero4 = {0.f, 0.f, 0.f, 0.f};

    bf16x8 qa0 = *(const bf16x8*)(Qb + (size_t)(q0 + lq) * 64 + lg * 8);
    bf16x8 qa1 = *(const bf16x8*)(Qb + (size_t)(q0 + lq) * 64 + 32 + lg * 8);

    f32x4 acc[4] = {zero4, zero4, zero4, zero4};
    float mrow = -1e30f;
    float lrow = 0.f;

    bf16x8 Kc[4], Vc[4], Kn[4], Vn[4];
    int kt = w;
    if (kt < nt) {
        const size_t tb = (size_t)kt * 2048;
        #pragma unroll
        for (int i = 0; i < 4; ++i) {
            Kc[i] = *(const bf16x8*)(KVbase_k + tb + i * 512);
            Vc[i] = *(const bf16x8*)(KVbase_v + tb + i * 512);
        }
    }

    for (; kt < nt; kt += 4) {
        const int ktn = kt + 4;
        if (ktn < nt) {   // prefetch next tile (coalesced 1KB loads)
            const size_t tb = (size_t)ktn * 2048;
            #pragma unroll
            for (int i = 0; i < 4; ++i) {
                Kn[i] = *(const bf16x8*)(KVbase_k + tb + i * 512);
                Vn[i] = *(const bf16x8*)(KVbase_v + tb + i * 512);
            }
        }

        const int key0 = kt * 32;
        f32x4 s[2];
        s[0] = __builtin_amdgcn_mfma_f32_16x16x32_bf16(Kc[0], qa0, zero4, 0, 0, 0);
        s[0] = __builtin_amdgcn_mfma_f32_16x16x32_bf16(Kc[1], qa1, s[0], 0, 0, 0);
        s[1] = __builtin_amdgcn_mfma_f32_16x16x32_bf16(Kc[2], qa0, zero4, 0, 0, 0);
        s[1] = __builtin_amdgcn_mfma_f32_16x16x32_bf16(Kc[3], qa1, s[1], 0, 0, 0);

        if (kt == nt - 1) {   // only the diagonal tile needs masking
            const int q = q0 + lq;
            #pragma unroll
            for (int fa = 0; fa < 2; ++fa)
                #pragma unroll
                for (int r = 0; r < 4; ++r) {
                    const int key = key0 + fa * 16 + 4 * lg + r;
                    if (key > q) s[fa][r] = -1e30f;
                }
        }

        float m1 = fmaxf(fmaxf(s[0][0], s[0][1]), s[0][2]);
        float m2 = fmaxf(fmaxf(s[0][3], s[1][0]), s[1][1]);
        float m3 = fmaxf(fmaxf(s[1][2], s[1][3]), m1);
        float tm = fmaxf(m2, m3);
        tm = fmaxf(tm, __shfl_xor(tm, 16));
        tm = fmaxf(tm, __shfl_xor(tm, 32));

        // defer-max: only rescale when max grows by > 8 (P bounded by 2^8)
        if (!__all(tm <= mrow + 8.0f)) {
            const float mnew = fmaxf(mrow, tm);
            const float cc = __builtin_amdgcn_exp2f(mrow - mnew);
            lrow *= cc;
            float cb[4];
            #pragma unroll
            for (int i = 0; i < 4; ++i) cb[i] = __shfl(cc, 4 * lg + i);
            #pragma unroll
            for (int nf = 0; nf < 4; ++nf)
                #pragma unroll
                for (int i = 0; i < 4; ++i) acc[nf][i] *= cb[i];
            mrow = mnew;
        }

        float p[2][4];
        float psum = 0.f;
        #pragma unroll
        for (int fa = 0; fa < 2; ++fa)
            #pragma unroll
            for (int r = 0; r < 4; ++r) {
                p[fa][r] = __builtin_amdgcn_exp2f(s[fa][r] - mrow);
                psum += p[fa][r];
            }
        psum += __shfl_xor(psum, 16);
        psum += __shfl_xor(psum, 32);
        lrow += psum;

        bf16x8 pa;
        pa[0] = (short)f2bf(p[0][0]); pa[1] = (short)f2bf(p[0][1]);
        pa[2] = (short)f2bf(p[0][2]); pa[3] = (short)f2bf(p[0][3]);
        pa[4] = (short)f2bf(p[1][0]); pa[5] = (short)f2bf(p[1][1]);
        pa[6] = (short)f2bf(p[1][2]); pa[7] = (short)f2bf(p[1][3]);

        acc[0] = __builtin_amdgcn_mfma_f32_16x16x32_bf16(pa, Vc[0], acc[0], 0, 0, 0);
        acc[1] = __builtin_amdgcn_mfma_f32_16x16x32_bf16(pa, Vc[1], acc[1], 0, 0, 0);
        acc[2] = __builtin_amdgcn_mfma_f32_16x16x32_bf16(pa, Vc[2], acc[2], 0, 0, 0);
        acc[3] = __builtin_amdgcn_mfma_f32_16x16x32_bf16(pa, Vc[3], acc[3], 0, 0, 0);

        #pragma unroll
        for (int i = 0; i < 4; ++i) { Kc[i] = Kn[i]; Vc[i] = Vn[i]; }
    }

    // store partial state to LDS
    if (lg == 0) {
        lm[w][lq] = mrow;
        ll[w][lq] = lrow;
    }
    #pragma unroll
    for (int nf = 0; nf < 4; ++nf)
        #pragma unroll
        for (int i = 0; i < 4; ++i)
            facc[w][(4 * lg + i) * 64 + nf * 16 + lq] = acc[nf][i];

    __syncthreads();

    // merge 4 wave-partials and write Out
    #pragma unroll
    for (int ii = 0; ii < 4; ++ii) {
        const int e = tid + ii * 256;
        const int q = e >> 6;
        const int h = e & 63;
        const float M = fmaxf(fmaxf(lm[0][q], lm[1][q]),
                              fmaxf(lm[2][q], lm[3][q]));
        float L = 0.f, O = 0.f;
        #pragma unroll
        for (int c = 0; c < 4; ++c) {
            const float wgt = __builtin_amdgcn_exp2f(lm[c][q] - M);
            L += wgt * ll[c][q];
            O += wgt * facc[c][q * 64 + h];
        }
        Out[((size_t)b * TN + q0 + q) * 64 + h] = O / L;
    }
}

extern "C" void kernel_launch(void* const* d_in, const int* in_sizes, int n_in,
                              void* d_out, int out_size, void* d_ws, size_t ws_size,
                              hipStream_t stream) {
    const float* X  = (const float*)d_in[0];
    const float* Wq = (const float*)d_in[1];
    const float* Wk = (const float*)d_in[2];
    const float* Wv = (const float*)d_in[3];
    float* Out = (float*)d_out;

    char* ws = (char*)d_ws;
    unsigned short* Wp = (unsigned short*)(ws);                 // 384 KB (pad 512 KB)
    unsigned short* Qs = (unsigned short*)(ws + (512u << 10));  // 2 MB
    unsigned short* Kp = Qs + (size_t)16384 * 64;               // 2 MB
    unsigned short* Vp = Kp + (size_t)16384 * 64;               // 2 MB

    hipLaunchKernelGGL(wconv_kernel, dim3(768), dim3(256), 0, stream, Wq, Wk, Wv, Wp);
    hipLaunchKernelGGL(proj_kernel,  dim3(512), dim3(512), 0, stream, X, Wp, Qs, Kp, Vp);
    hipLaunchKernelGGL(attn_kernel,  dim3(1024), dim3(256), 0, stream, Qs, Kp, Vp, Out);
}

// Round 8
// 42.509 us; speedup vs baseline: 3.0343x; 1.0107x over previous
//
#include <hip/hip_runtime.h>
#include <hip/hip_bf16.h>
#include <cstdint>
#include <cstddef>

typedef short bf16x8 __attribute__((ext_vector_type(8)));
typedef float f32x4 __attribute__((ext_vector_type(4)));

#define BN 8
#define TN 2048
#define CN 1024
#define HN 64

__device__ __forceinline__ unsigned short f2bf(float f) {
    unsigned int u = __float_as_uint(f);
    u += 0x7fffu + ((u >> 16) & 1u);
    return (unsigned short)(u >> 16);
}

// packed f32x2 -> bf16x2 (v_cvt_pk_bf16_f32), lo in low half
__device__ __forceinline__ int pk2(float lo, float hi) {
    float2 t; t.x = lo; t.y = hi;
    __hip_bfloat162 h = __float22bfloat162_rn(t);
    return *reinterpret_cast<int*>(&h);
}

// async global->LDS copy, 16 B per lane; ldst must be the WAVE-UNIFORM base
// (HW adds lane*16), gsrc is per-lane.
__device__ __forceinline__ void gload_lds16(const unsigned short* gsrc, void* ldst) {
    __builtin_amdgcn_global_load_lds(
        (const __attribute__((address_space(1))) unsigned int*)gsrc,
        (__attribute__((address_space(3))) unsigned int*)ldst,
        16, 0, 0);
}

// Build Wp: W in MFMA-B-fragment-packed order.
// Logical Wct[n][c], n in [0,192): n<64 = Wq col h (pre-scaled by 0.125*log2e),
// 64..127 = Wk, 128..191 = Wv.  Fragment (tile=n>>4, kk=c>>5): lane = lg*16+lq
// (lg=(c>>3)&3, lq=n&15), elem e=c&7.
// idx = ((tile*32+kk)*64 + lg*16 + lq)*8 + e  -> wave loads are lane-contiguous.
__global__ __launch_bounds__(256) void wconv_kernel(const float* __restrict__ Wq,
                                                    const float* __restrict__ Wk,
                                                    const float* __restrict__ Wv,
                                                    unsigned short* __restrict__ Wp) {
    int idx = blockIdx.x * 256 + threadIdx.x;   // 0..196607
    int n = idx >> 10;
    int c = idx & 1023;
    int m = n >> 6;
    int h = n & 63;
    const float* W = (m == 0) ? Wq : ((m == 1) ? Wk : Wv);
    float v = W[c * 64 + h];
    if (m == 0) v *= 0.18033688011112042f;  // (1/sqrt(64)) * log2(e)
    const int tile = n >> 4, lq = n & 15;
    const int kk = c >> 5, lg = (c >> 3) & 3, e = c & 7;
    Wp[(size_t)(((tile * 32 + kk) * 64 + lg * 16 + lq) * 8 + e)] = f2bf(v);
}

// Fused QKV projection v8: m97-style double-buffered LDS pipeline.
// W staged via async global_load_lds (issued BEFORE current-step compute,
// drains at the per-step barrier -> latency hidden); X reg-staged + cvt.
// 512 blocks x 512 threads (8 waves).  BM=32, BN=192, BK=64, 16 K-steps.
__global__ __launch_bounds__(512) void proj_kernel(const float* __restrict__ X,
                                                   const unsigned short* __restrict__ Wp,
                                                   unsigned short* __restrict__ Qs,
                                                   unsigned short* __restrict__ Kp,
                                                   unsigned short* __restrict__ Vp) {
    __shared__ short Xs[2][32 * 64];      // 2 x 4 KB bf16
    __shared__ short Wsh[2][12288];       // 2 x 24 KB bf16

    const int tid = threadIdx.x;
    const int w   = tid >> 6;       // 0..7
    const int l   = tid & 63;
    const int lq  = l & 15;
    const int lg  = l >> 4;
    const int wr  = w >> 2;         // M-half
    const int wc  = w & 3;          // N-quarter
    const int rowbase = blockIdx.x * 32;

    // --- X staging addresses (per thread) ---
    const int xrow = tid >> 4;             // 0..31
    const int xcol = (tid & 15) * 4;       // 0..60 (floats)
    const float* xsrc = X + (size_t)(rowbase + xrow) * CN + xcol;
    const int xdst = xrow * 128 + (((tid & 15) * 8) ^ ((xrow & 7) << 4));  // byte

    // --- W staging: per-wave chunk j*4096 + w*512 elems, lane-contiguous ---
    const unsigned short* wsrc[3];
    int wbase[3];                          // wave-uniform LDS elem offset
    #pragma unroll
    for (int j = 0; j < 3; ++j) {
        const int el  = j * 4096 + tid * 8;       // this thread's first elem
        const int blk = el >> 9;
        const int t   = blk >> 1, kkL = blk & 1;
        wsrc[j]  = Wp + (t * 32 + kkL) * 512 + (el & 511);
        wbase[j] = j * 4096 + w * 512;            // uniform across the wave
    }

    // --- compute-side LDS addresses (per lane) ---
    const int arow = wr * 16 + lq;
    int aaddr[2];
    #pragma unroll
    for (int kkL = 0; kkL < 2; ++kkL)
        aaddr[kkL] = arow * 128 + (((kkL * 64 + lg * 16)) ^ ((arow & 7) << 4));
    int baddr[2][3];
    #pragma unroll
    for (int kkL = 0; kkL < 2; ++kkL)
        #pragma unroll
        for (int jj = 0; jj < 3; ++jj)
            baddr[kkL][jj] = (((wc * 3 + jj) * 2 + kkL) * 64 + l) * 16;  // byte

    const f32x4 zero4 = {0.f, 0.f, 0.f, 0.f};
    f32x4 acc[3] = {zero4, zero4, zero4};

    // --- prologue: stage step 0 into buffer 0 ---
    {
        #pragma unroll
        for (int j = 0; j < 3; ++j)
            gload_lds16(wsrc[j], (char*)Wsh[0] + wbase[j] * 2);
        float4 xr = *(const float4*)(xsrc);
        int2 xc; xc.x = pk2(xr.x, xr.y); xc.y = pk2(xr.z, xr.w);
        *(int2*)((char*)Xs[0] + xdst) = xc;
        __syncthreads();   // drains vmcnt (gload_lds) + lgkm (ds_write)
    }

    for (int s = 0; s < 16; ++s) {
        const int cur = s & 1;
        const int nxt = cur ^ 1;
        const bool more = (s + 1) < 16;
        // 1) issue next step's async W copies + X load BEFORE compute
        float4 xr;
        if (more) {
            #pragma unroll
            for (int j = 0; j < 3; ++j)
                gload_lds16(wsrc[j] + (s + 1) * 1024, (char*)Wsh[nxt] + wbase[j] * 2);
            xr = *(const float4*)(xsrc + (s + 1) * 64);
        }
        // 2) compute current buffer
        #pragma unroll
        for (int kkL = 0; kkL < 2; ++kkL) {
            bf16x8 a  = *(const bf16x8*)((char*)Xs[cur] + aaddr[kkL]);
            bf16x8 b0 = *(const bf16x8*)((char*)Wsh[cur] + baddr[kkL][0]);
            bf16x8 b1 = *(const bf16x8*)((char*)Wsh[cur] + baddr[kkL][1]);
            bf16x8 b2 = *(const bf16x8*)((char*)Wsh[cur] + baddr[kkL][2]);
            acc[0] = __builtin_amdgcn_mfma_f32_16x16x32_bf16(a, b0, acc[0], 0, 0, 0);
            acc[1] = __builtin_amdgcn_mfma_f32_16x16x32_bf16(a, b1, acc[1], 0, 0, 0);
            acc[2] = __builtin_amdgcn_mfma_f32_16x16x32_bf16(a, b2, acc[2], 0, 0, 0);
        }
        // 3) convert + write next X buffer
        if (more) {
            int2 xc; xc.x = pk2(xr.x, xr.y); xc.y = pk2(xr.z, xr.w);
            *(int2*)((char*)Xs[nxt] + xdst) = xc;
        }
        // 4) one barrier per K-step (drains async W copies + X writes)
        __syncthreads();
    }

    // D layout: col = lane&15 (W col), row = 4*(lane>>4) + reg (X row)
    #pragma unroll
    for (int j = 0; j < 3; ++j) {
        const int col = wc * 48 + j * 16 + lq;
        const int mtx = col >> 6;          // 0=Q, 1=K, 2=V
        const int h   = col & 63;
        #pragma unroll
        for (int i = 0; i < 4; ++i) {
            const int g = rowbase + wr * 16 + 4 * lg + i;   // global token row
            const unsigned short val = f2bf(acc[j][i]);
            const int b = g >> 11, tloc = g & 2047;
            const int kt = tloc >> 5;
            if (mtx == 0) {
                Qs[(size_t)g * 64 + h] = val;
            } else if (mtx == 1) {
                // K fragment-packed: frag = fa*2+ks, lane = lgk*16+lqk, elem e
                const int fa = (tloc >> 4) & 1, lqk = tloc & 15;
                const int ks = h >> 5, lgk = (h >> 3) & 3, e = h & 7;
                Kp[(size_t)(b * 64 + kt) * 2048 + (fa * 2 + ks) * 512 +
                   (lgk * 16 + lqk) * 8 + e] = val;
            } else {
                // V fragment-packed: frag = nf, lane = lgv*16+lqv, elem e
                const int tt = tloc & 31;
                const int lgv = (tt & 15) >> 2;
                const int e = (tt < 16) ? (tt & 3) : 4 + (tt & 3);
                const int nf = h >> 4, lqv = h & 15;
                Vp[(size_t)(b * 64 + kt) * 2048 + nf * 512 +
                   (lgv * 16 + lqv) * 8 + e] = val;
            }
        }
    }
}

// Block-cooperative causal flash attention, fragment-packed K/V.
// Block = (qt, b): 1024 blocks x 4 waves; heavy q-tiles launch first.
// Waves split the q-tile's key-tiles round-robin; partials merged in LDS.
// S^T = mfma(K, Q): lane&15 = query, key = 16*fa + 4*(lane>>4) + reg.
__global__ __launch_bounds__(256) void attn_kernel(const unsigned short* __restrict__ Qs,
                                                   const unsigned short* __restrict__ Kp,
                                                   const unsigned short* __restrict__ Vp,
                                                   float* __restrict__ Out) {
    __shared__ float lm[4][16];
    __shared__ float ll[4][16];
    __shared__ float facc[4][1024];

    const int tid = threadIdx.x;
    const int w  = tid >> 6;
    const int l  = tid & 63;
    const int lq = l & 15;
    const int lg = l >> 4;
    const int bid = blockIdx.x;
    const int qt = 127 - (bid >> 3);   // heavy first
    const int b  = bid & 7;
    const int q0 = qt * 16;
    const int nt = (qt >> 1) + 1;

    const unsigned short* Qb = Qs + (size_t)b * TN * 64;
    const unsigned short* KVbase_k = Kp + (size_t)b * 64 * 2048 + (size_t)l * 8;
    const unsigned short* KVbase_v = Vp + (size_t)b * 64 * 2048 + (size_t)l * 8;

    const f32x4 zero4 = {0.f, 0.f, 0.f, 0.f};

    bf16x8 qa0 = *(const bf16x8*)(Qb + (size_t)(q0 + lq) * 64 + lg * 8);
    bf16x8 qa1 = *(const bf16x8*)(Qb + (size_t)(q0 + lq) * 64 + 32 + lg * 8);

    f32x4 acc[4] = {zero4, zero4, zero4, zero4};
    float mrow = -1e30f;
    float lrow = 0.f;

    bf16x8 Kc[4], Vc[4], Kn[4], Vn[4];
    int kt = w;
    if (kt < nt) {
        const size_t tb = (size_t)kt * 2048;
        #pragma unroll
        for (int i = 0; i < 4; ++i) {
            Kc[i] = *(const bf16x8*)(KVbase_k + tb + i * 512);
            Vc[i] = *(const bf16x8*)(KVbase_v + tb + i * 512);
        }
    }

    for (; kt < nt; kt += 4) {
        const int ktn = kt + 4;
        if (ktn < nt) {   // prefetch next tile (coalesced 1KB loads)
            const size_t tb = (size_t)ktn * 2048;
            #pragma unroll
            for (int i = 0; i < 4; ++i) {
                Kn[i] = *(const bf16x8*)(KVbase_k + tb + i * 512);
                Vn[i] = *(const bf16x8*)(KVbase_v + tb + i * 512);
            }
        }

        const int key0 = kt * 32;
        f32x4 s[2];
        s[0] = __builtin_amdgcn_mfma_f32_16x16x32_bf16(Kc[0], qa0, zero4, 0, 0, 0);
        s[0] = __builtin_amdgcn_mfma_f32_16x16x32_bf16(Kc[1], qa1, s[0], 0, 0, 0);
        s[1] = __builtin_amdgcn_mfma_f32_16x16x32_bf16(Kc[2], qa0, zero4, 0, 0, 0);
        s[1] = __builtin_amdgcn_mfma_f32_16x16x32_bf16(Kc[3], qa1, s[1], 0, 0, 0);

        if (kt == nt - 1) {   // only the diagonal tile needs masking
            const int q = q0 + lq;
            #pragma unroll
            for (int fa = 0; fa < 2; ++fa)
                #pragma unroll
                for (int r = 0; r < 4; ++r) {
                    const int key = key0 + fa * 16 + 4 * lg + r;
                    if (key > q) s[fa][r] = -1e30f;
                }
        }

        float m1 = fmaxf(fmaxf(s[0][0], s[0][1]), s[0][2]);
        float m2 = fmaxf(fmaxf(s[0][3], s[1][0]), s[1][1]);
        float m3 = fmaxf(fmaxf(s[1][2], s[1][3]), m1);
        float tm = fmaxf(m2, m3);
        tm = fmaxf(tm, __shfl_xor(tm, 16));
        tm = fmaxf(tm, __shfl_xor(tm, 32));

        // defer-max: only rescale when max grows by > 8 (P bounded by 2^8)
        if (!__all(tm <= mrow + 8.0f)) {
            const float mnew = fmaxf(mrow, tm);
            const float cc = __builtin_amdgcn_exp2f(mrow - mnew);
            lrow *= cc;
            float cb[4];
            #pragma unroll
            for (int i = 0; i < 4; ++i) cb[i] = __shfl(cc, 4 * lg + i);
            #pragma unroll
            for (int nf = 0; nf < 4; ++nf)
                #pragma unroll
                for (int i = 0; i < 4; ++i) acc[nf][i] *= cb[i];
            mrow = mnew;
        }

        float p[2][4];
        float psum = 0.f;
        #pragma unroll
        for (int fa = 0; fa < 2; ++fa)
            #pragma unroll
            for (int r = 0; r < 4; ++r) {
                p[fa][r] = __builtin_amdgcn_exp2f(s[fa][r] - mrow);
                psum += p[fa][r];
            }
        psum += __shfl_xor(psum, 16);
        psum += __shfl_xor(psum, 32);
        lrow += psum;

        bf16x8 pa;
        pa[0] = (short)f2bf(p[0][0]); pa[1] = (short)f2bf(p[0][1]);
        pa[2] = (short)f2bf(p[0][2]); pa[3] = (short)f2bf(p[0][3]);
        pa[4] = (short)f2bf(p[1][0]); pa[5] = (short)f2bf(p[1][1]);
        pa[6] = (short)f2bf(p[1][2]); pa[7] = (short)f2bf(p[1][3]);

        acc[0] = __builtin_amdgcn_mfma_f32_16x16x32_bf16(pa, Vc[0], acc[0], 0, 0, 0);
        acc[1] = __builtin_amdgcn_mfma_f32_16x16x32_bf16(pa, Vc[1], acc[1], 0, 0, 0);
        acc[2] = __builtin_amdgcn_mfma_f32_16x16x32_bf16(pa, Vc[2], acc[2], 0, 0, 0);
        acc[3] = __builtin_amdgcn_mfma_f32_16x16x32_bf16(pa, Vc[3], acc[3], 0, 0, 0);

        #pragma unroll
        for (int i = 0; i < 4; ++i) { Kc[i] = Kn[i]; Vc[i] = Vn[i]; }
    }

    // store partial state to LDS
    if (lg == 0) {
        lm[w][lq] = mrow;
        ll[w][lq] = lrow;
    }
    #pragma unroll
    for (int nf = 0; nf < 4; ++nf)
        #pragma unroll
        for (int i = 0; i < 4; ++i)
            facc[w][(4 * lg + i) * 64 + nf * 16 + lq] = acc[nf][i];

    __syncthreads();

    // merge 4 wave-partials and write Out
    #pragma unroll
    for (int ii = 0; ii < 4; ++ii) {
        const int e = tid + ii * 256;
        const int q = e >> 6;
        const int h = e & 63;
        const float M = fmaxf(fmaxf(lm[0][q], lm[1][q]),
                              fmaxf(lm[2][q], lm[3][q]));
        float L = 0.f, O = 0.f;
        #pragma unroll
        for (int c = 0; c < 4; ++c) {
            const float wgt = __builtin_amdgcn_exp2f(lm[c][q] - M);
            L += wgt * ll[c][q];
            O += wgt * facc[c][q * 64 + h];
        }
        Out[((size_t)b * TN + q0 + q) * 64 + h] = O / L;
    }
}

extern "C" void kernel_launch(void* const* d_in, const int* in_sizes, int n_in,
                              void* d_out, int out_size, void* d_ws, size_t ws_size,
                              hipStream_t stream) {
    const float* X  = (const float*)d_in[0];
    const float* Wq = (const float*)d_in[1];
    const float* Wk = (const float*)d_in[2];
    const float* Wv = (const float*)d_in[3];
    float* Out = (float*)d_out;

    char* ws = (char*)d_ws;
    unsigned short* Wp = (unsigned short*)(ws);                 // 384 KB (pad 512 KB)
    unsigned short* Qs = (unsigned short*)(ws + (512u << 10));  // 2 MB
    unsigned short* Kp = Qs + (size_t)16384 * 64;               // 2 MB
    unsigned short* Vp = Kp + (size_t)16384 * 64;               // 2 MB

    hipLaunchKernelGGL(wconv_kernel, dim3(768), dim3(256), 0, stream, Wq, Wk, Wv, Wp);
    hipLaunchKernelGGL(proj_kernel,  dim3(512), dim3(512), 0, stream, X, Wp, Qs, Kp, Vp);
    hipLaunchKernelGGL(attn_kernel,  dim3(1024), dim3(256), 0, stream, Qs, Kp, Vp, Out);
}